// Round 7
// baseline (288.206 us; speedup 1.0000x reference)
//
#include <hip/hip_runtime.h>

// x (B,K,D) f32, w (1,K,D) f32 -> out (S*B, K, D) f32
// out[s*B+b, k, d] = exp(-d2[b,d] * inv[s]),  d2[b,d] = sum_k (x[b,k,d]-w[k,d])^2
#define BB 128
#define KK 49
#define DD 2048
#define SS 5
#define D2N (DD / 2)  // 1024 float2 per row

// Native clang vector type: __builtin_nontemporal_store requires a pointer to
// int/float/ptr or a NATIVE vector of such — HIP's float2 (a class) is rejected.
typedef float f32x2 __attribute__((ext_vector_type(2)));

__global__ __launch_bounds__(256) void rbf_broadcast_kernel(
    const float* __restrict__ x, const float* __restrict__ w,
    float* __restrict__ out) {
  // grid = BB * 4 blocks of 256 threads; each thread owns one float2 of (b, d).
  const int chunk = blockIdx.x & 3;              // 4 chunks of 256 float2
  const int b     = blockIdx.x >> 2;
  const int d2i   = chunk * 256 + threadIdx.x;   // [0, 1024)

  const f32x2* xp = (const f32x2*)x + (size_t)b * (KK * D2N) + d2i;
  const f32x2* wp = (const f32x2*)w + d2i;

  float ax = 0.f, ay = 0.f;
#pragma unroll
  for (int k = 0; k < KK; ++k) {
    f32x2 xv = xp[(size_t)k * D2N];
    f32x2 wv = wp[(size_t)k * D2N];
    float dx = xv.x - wv.x;
    float dy = xv.y - wv.y;
    ax = fmaf(dx, dx, ax);
    ay = fmaf(dy, dy, ay);
  }

  // inv[s] = 1/(2*sigma^2), sigma = 1..5
  const float inv[SS] = {0.5f, 0.125f, 1.0f / 18.0f, 0.03125f, 0.02f};

#pragma unroll
  for (int s = 0; s < SS; ++s) {
    f32x2 e;
    e.x = expf(-ax * inv[s]);
    e.y = expf(-ay * inv[s]);
    f32x2* op = (f32x2*)out + ((size_t)(s * BB + b) * KK) * D2N + d2i;
#pragma unroll
    for (int k = 0; k < KK; ++k) {
      __builtin_nontemporal_store(e, op + (size_t)k * D2N);
    }
  }
}

extern "C" void kernel_launch(void* const* d_in, const int* in_sizes, int n_in,
                              void* d_out, int out_size, void* d_ws,
                              size_t ws_size, hipStream_t stream) {
  const float* x = (const float*)d_in[0];
  const float* w = (const float*)d_in[1];
  float* out = (float*)d_out;
  dim3 grid(BB * 4);
  dim3 block(256);
  rbf_broadcast_kernel<<<grid, block, 0, stream>>>(x, w, out);
}